// Round 8
// baseline (289.739 us; speedup 1.0000x reference)
//
#include <hip/hip_runtime.h>

// B=8, T=1024, D=1024, H=16, DH=64.
// Column softmax (axis=-2): attn[q,k] = exp(S[q,k])/sum_q' exp(S[q',k]).
// rcpL folded into V (Vts = V * rcpL), so K3 is O = exp2(S*C2) @ Vts.
// K3 computes S TRANSPOSED (A=K, B=Q) so the P fragment exits MFMA with
// q=lane&15 and k=quad*4+t -- which is EXACTLY the B-operand layout of the
// K=16 MFMA (16x16x16_bf16). PV therefore consumes P fully in-register.
// Vts is stored k-PERMUTED (within each 32-chunk: pos quad*8+kk*4+t holds
// logical k=kk*16+quad*4+t) so the PV A-fragment is ONE contiguous bf16x8
// load whose lo/hi halves are the two K=16 A-fragments (free reg aliasing).
// R3: Vts tile staged in LDS (dbuf, global_load_lds, XOR-swizzled).
// R4: runtime-indexed LDS dbuf -> alias-conservative vmcnt drain. REVERTED.
// R6: single-buffer BK=64: K1=64.4us / 800 TF (verified).
// R7: static dbuf: K1 REGRESSED (69.8us, occ 25.6->18.9, FETCH 58->116MB)
// but END-TO-END improved (282->271) -- the win is K4 (512 blocks = 2/CU,
// no inter-block overlap to lean on -> dbuf's wave-internal hiding pays;
// K1's 1536 blocks already overlap inter-block -> dbuf only costs L2/occ).
// R8: regime-matched routing -- K1 uses single-buffer gemm_bt (R6 body),
// K4 uses static-dbuf gemm_bt_db (R7 body). No new structures.

typedef __bf16 bf16_t;
typedef __bf16 bf16x8 __attribute__((ext_vector_type(8)));
typedef __bf16 bf16x4 __attribute__((ext_vector_type(4)));
typedef float f32x4 __attribute__((ext_vector_type(4)));
typedef unsigned short u16x8 __attribute__((ext_vector_type(8)));
typedef short s16x4 __attribute__((ext_vector_type(4)));

#define DEV __device__ __forceinline__
#define C2 0.18033688f  // DH^-0.5 * log2(e)

DEV void gld_lds16(const bf16_t* g, bf16_t* l) {
  __builtin_amdgcn_global_load_lds(
      (const __attribute__((address_space(1))) unsigned int*)g,
      (__attribute__((address_space(3))) unsigned int*)l, 16, 0, 0);
}

// exp2 via v_exp_f32; upper clamp only (underflow->0 fine); finite always.
DEV float exp2c(float x) { return __builtin_amdgcn_exp2f(fminf(x, 30.f)); }
DEV float sanit(float v) { return (v == v) ? fminf(fmaxf(v, -1e4f), 1e4f) : 0.f; }

// Swizzled chunk (8 bf16 = 16B) offsets in elements. Swizzle baked into the
// staging GLOBAL address so the LDS side stays linear (global_load_lds req).
DEV int sw64(int r, int kc) { return r * 64 + (((kc ^ (r + (r >> 3))) & 7) << 3); }

DEV f32x4 mfma16(bf16x8 a, bf16x8 b, f32x4 c) {
  return __builtin_amdgcn_mfma_f32_16x16x32_bf16(a, b, c, 0, 0, 0);
}

// K=16 bf16 MFMA: A[m=l][k=quad*4+j], B[n=l][k=quad*4+j], D row=quad*4+t col=l.
DEV f32x4 mfma16k16(bf16x4 a, bf16x4 b, f32x4 c) {
#if defined(__has_builtin) && __has_builtin(__builtin_amdgcn_mfma_f32_16x16x16bf16_1k)
  union U { bf16x4 h; s16x4 s; };
  U ua, ub;
  ua.h = a;
  ub.h = b;
  return __builtin_amdgcn_mfma_f32_16x16x16bf16_1k(ua.s, ub.s, c, 0, 0, 0);
#else
  f32x4 d;
  asm("v_mfma_f32_16x16x16_bf16 %0, %1, %2, %3"
      : "=v"(d)
      : "v"(a), "v"(b), "v"(c));
  return d;
#endif
}

DEV bf16x4 lo4(bf16x8 v) { return __builtin_shufflevector(v, v, 0, 1, 2, 3); }
DEV bf16x4 hi4(bf16x8 v) { return __builtin_shufflevector(v, v, 4, 5, 6, 7); }

// ---- dtype probe: bf16 data has exp<=~134; fp32 misread shows exp>=160 -----
__global__ void detect_dtype(const unsigned short* x, int* flag) {
  __shared__ int smax;
  if (threadIdx.x == 0) smax = 0;
  __syncthreads();
  int m = 0;
  for (int i = threadIdx.x; i < 16384; i += 256) {
    int e = (x[i] >> 7) & 0xFF;
    m = m > e ? m : e;
  }
  atomicMax(&smax, m);
  __syncthreads();
  if (threadIdx.x == 0) *flag = (smax >= 160) ? 1 : 0;
}

// ---- canonicalize all 3 inputs to bf16 in one kernel ------------------------
__global__ void convert_in(const void* __restrict__ x, const void* __restrict__ wq,
                           const void* __restrict__ wp, bf16_t* __restrict__ xb,
                           bf16_t* __restrict__ wqb, bf16_t* __restrict__ wpb,
                           const int* __restrict__ flag) {
  int i = blockIdx.x * 256 + threadIdx.x;  // vec8 index, total 1572864
  const void* src;
  bf16_t* dst;
  int off;
  if (i < 1048576) { src = x; dst = xb; off = i; }
  else if (i < 1441792) { src = wq; dst = wqb; off = i - 1048576; }
  else { src = wp; dst = wpb; off = i - 1441792; }
  if (*flag) {
    const float4* s = (const float4*)src;
    float4 a = s[off * 2], b = s[off * 2 + 1];
    bf16x8 o;
    o[0] = (bf16_t)a.x; o[1] = (bf16_t)a.y; o[2] = (bf16_t)a.z; o[3] = (bf16_t)a.w;
    o[4] = (bf16_t)b.x; o[5] = (bf16_t)b.y; o[6] = (bf16_t)b.z; o[7] = (bf16_t)b.w;
    *(bf16x8*)(dst + (size_t)off * 8) = o;
  } else {
    ((u16x8*)dst)[off] = ((const u16x8*)src)[off];
  }
}

// --------- C[m][n] = sum_k A[m][k]*B[n][k], 128x128 tile, BK=64 -------------
// SINGLE-BUFFER, 2 barriers per K-step (R6, verified 64.4us/800TF on K1).
// For grids with many blocks/CU: inter-block overlap hides stage latency;
// dbuf here only costs occupancy + L2 locality (R7 measured).
__global__ __launch_bounds__(256, 2)
void gemm_bt(const bf16_t* __restrict__ A, int lda, const bf16_t* __restrict__ B,
             bf16_t* __restrict__ Cb, float* __restrict__ Cf, int ldc,
             int K, const int* __restrict__ f32flag) {
  __shared__ bf16_t sA[128 * 64];  // 16 KB
  __shared__ bf16_t sB[128 * 64];  // 16 KB
  const int tid = threadIdx.x;
  const int wave = tid >> 6, lane = tid & 63;
  const int l = lane & 15, quad = lane >> 4;
  const int nwg = gridDim.x * gridDim.y;
  const int bid = blockIdx.y * gridDim.x + blockIdx.x;
  const int sb = (bid & 7) * (nwg >> 3) + (bid >> 3);
  const int row0 = (sb / gridDim.x) * 128, col0 = (sb % gridDim.x) * 128;
  const int wm = (wave >> 1) * 64, wn = (wave & 1) * 64;
  f32x4 acc[4][4];
#pragma unroll
  for (int i = 0; i < 4; ++i)
#pragma unroll
    for (int j = 0; j < 4; ++j) acc[i][j] = f32x4{0.f, 0.f, 0.f, 0.f};

  for (int k0 = 0; k0 < K; k0 += 64) {
    __syncthreads();
#pragma unroll
    for (int t = 0; t < 4; ++t) {
      int n = t * 256 + tid;
      int r = n >> 3;
      int kc = ((n & 7) ^ (r + (r >> 3))) & 7;
      gld_lds16(A + (size_t)(row0 + r) * lda + k0 + kc * 8, sA + n * 8);
      gld_lds16(B + (size_t)(col0 + r) * K + k0 + kc * 8, sB + n * 8);
    }
    __syncthreads();
#pragma unroll
    for (int ks = 0; ks < 2; ++ks) {
      bf16x8 af[4], bfr[4];
#pragma unroll
      for (int i = 0; i < 4; ++i)
        af[i] = *(const bf16x8*)&sA[sw64(wm + i * 16 + l, ks * 4 + quad)];
#pragma unroll
      for (int j = 0; j < 4; ++j)
        bfr[j] = *(const bf16x8*)&sB[sw64(wn + j * 16 + l, ks * 4 + quad)];
#pragma unroll
      for (int i = 0; i < 4; ++i)
#pragma unroll
        for (int j = 0; j < 4; ++j)
          acc[i][j] = mfma16(af[i], bfr[j], acc[i][j]);
    }
  }
  const bool of32 = (f32flag != nullptr) && (*f32flag != 0);
#pragma unroll
  for (int i = 0; i < 4; ++i) {
    int rr = row0 + wm + i * 16 + quad * 4;
#pragma unroll
    for (int j = 0; j < 4; ++j) {
      int cc = col0 + wn + j * 16 + l;
#pragma unroll
      for (int t = 0; t < 4; ++t) {
        float v = sanit(acc[i][j][t]);
        size_t idx = (size_t)(rr + t) * ldc + cc;
        if (of32) Cf[idx] = v; else Cb[idx] = (bf16_t)v;
      }
    }
  }
}

// --------- gemm variant for FEW-BLOCK grids (~2 blocks/CU): static dbuf -----
// Statically-unrolled buf0/buf1 (4 distinct __shared__ arrays -> alias
// analysis resolves; R7 body). With no inter-block overlap available, the
// wave-internal stage/compute overlap is the win; occupancy already capped.
__global__ __launch_bounds__(256, 2)
void gemm_bt_db(const bf16_t* __restrict__ A, int lda, const bf16_t* __restrict__ B,
                bf16_t* __restrict__ Cb, float* __restrict__ Cf, int ldc,
                int K, const int* __restrict__ f32flag) {
  __shared__ bf16_t sA0[128 * 64];  // 16 KB
  __shared__ bf16_t sB0[128 * 64];
  __shared__ bf16_t sA1[128 * 64];
  __shared__ bf16_t sB1[128 * 64];
  const int tid = threadIdx.x;
  const int wave = tid >> 6, lane = tid & 63;
  const int l = lane & 15, quad = lane >> 4;
  const int nwg = gridDim.x * gridDim.y;
  const int bid = blockIdx.y * gridDim.x + blockIdx.x;
  const int sb = (bid & 7) * (nwg >> 3) + (bid >> 3);
  const int row0 = (sb / gridDim.x) * 128, col0 = (sb % gridDim.x) * 128;
  const int wm = (wave >> 1) * 64, wn = (wave & 1) * 64;
  f32x4 acc[4][4];
#pragma unroll
  for (int i = 0; i < 4; ++i)
#pragma unroll
    for (int j = 0; j < 4; ++j) acc[i][j] = f32x4{0.f, 0.f, 0.f, 0.f};

#define STAGE_G(sa, sb_, kk)                                                  \
  {                                                                           \
    _Pragma("unroll") for (int t = 0; t < 4; ++t) {                           \
      int n = t * 256 + tid;                                                  \
      int r = n >> 3;                                                         \
      int kc = ((n & 7) ^ (r + (r >> 3))) & 7;                                \
      gld_lds16(A + (size_t)(row0 + r) * lda + (kk) + kc * 8, (sa) + n * 8);  \
      gld_lds16(B + (size_t)(col0 + r) * K + (kk) + kc * 8, (sb_) + n * 8);   \
    }                                                                         \
  }

#define COMPUTE_G(sa, sb_)                                                    \
  {                                                                           \
    _Pragma("unroll") for (int ks = 0; ks < 2; ++ks) {                        \
      bf16x8 af[4], bfr[4];                                                   \
      _Pragma("unroll") for (int i = 0; i < 4; ++i) af[i] =                   \
          *(const bf16x8*)&(sa)[sw64(wm + i * 16 + l, ks * 4 + quad)];        \
      _Pragma("unroll") for (int j = 0; j < 4; ++j) bfr[j] =                  \
          *(const bf16x8*)&(sb_)[sw64(wn + j * 16 + l, ks * 4 + quad)];       \
      _Pragma("unroll") for (int i = 0; i < 4; ++i)                           \
          _Pragma("unroll") for (int j = 0; j < 4; ++j) acc[i][j] =           \
              mfma16(af[i], bfr[j], acc[i][j]);                               \
    }                                                                         \
  }

  STAGE_G(sA0, sB0, 0);
  for (int k0 = 0; k0 < K; k0 += 128) {
    __syncthreads();  // buf0 staged; also orders prev compute(buf1) vs refill
    if (k0 + 64 < K) STAGE_G(sA1, sB1, k0 + 64);
    COMPUTE_G(sA0, sB0);
    __syncthreads();  // buf1 staged; orders compute(buf0) vs buf0 refill
    if (k0 + 128 < K) STAGE_G(sA0, sB0, k0 + 128);
    COMPUTE_G(sA1, sB1);
  }
#undef STAGE_G
#undef COMPUTE_G

  const bool of32 = (f32flag != nullptr) && (*f32flag != 0);
#pragma unroll
  for (int i = 0; i < 4; ++i) {
    int rr = row0 + wm + i * 16 + quad * 4;
#pragma unroll
    for (int j = 0; j < 4; ++j) {
      int cc = col0 + wn + j * 16 + l;
#pragma unroll
      for (int t = 0; t < 4; ++t) {
        float v = sanit(acc[i][j][t]);
        size_t idx = (size_t)(rr + t) * ldc + cc;
        if (of32) Cf[idx] = v; else Cb[idx] = (bf16_t)v;
      }
    }
  }
}

// ------------- K2: column sumexp L[k]; write Vts = V * (1/L) -----------------
// Grid (bh, kt): same-bh blocks spaced 128 apart -> same XCD -> Q of that bh
// stays L2-hot. Per-lane accj[] defers reduction: 8 atomics/wave.
// Vts write is k-PERMUTED within each 32-chunk (see K3 header comment).
__global__ __launch_bounds__(256, 4)
void attn_stats(const bf16_t* __restrict__ qkv, bf16_t* __restrict__ Vts) {
  __shared__ bf16_t sK[128 * 64];
  __shared__ bf16_t sV[128 * 64];
  __shared__ float sL[128];
  const int bh = blockIdx.x, kt = blockIdx.y;
  const int b = bh >> 4, h = bh & 15;
  const int tid = threadIdx.x, wave = tid >> 6, lane = tid & 63;
  const int l = lane & 15, quad = lane >> 4;
  const size_t rowK = (size_t)b * 1024 + kt * 128;

  // stage V-tile and K-tile (swizzled)
#pragma unroll
  for (int t = 0; t < 4; ++t) {
    int base = wave * 256 + t * 64;
    int n = base + lane;
    int r = n >> 3;
    int kc = ((n & 7) ^ (r + (r >> 3))) & 7;
    gld_lds16(qkv + (rowK + r) * 3072 + 2048 + h * 64 + kc * 8, sV + base * 8);
    gld_lds16(qkv + (rowK + r) * 3072 + 1024 + h * 64 + kc * 8, sK + base * 8);
  }
  if (tid < 128) sL[tid] = 0.f;
  __syncthreads();

  float accj[8];
#pragma unroll
  for (int j = 0; j < 8; ++j) accj[j] = 0.f;

  for (int qt = 0; qt < 8; ++qt) {
    bf16x8 aq[2][2];
#pragma unroll
    for (int i = 0; i < 2; ++i)
#pragma unroll
      for (int ks = 0; ks < 2; ++ks)
        aq[i][ks] = *(const bf16x8*)&qkv[((size_t)b * 1024 + qt * 128 + wave * 32 +
                                          i * 16 + l) * 3072 + h * 64 +
                                         (ks * 4 + quad) * 8];
#pragma unroll
    for (int j = 0; j < 8; ++j) {
      f32x4 s0 = {0.f, 0.f, 0.f, 0.f}, s1 = {0.f, 0.f, 0.f, 0.f};
#pragma unroll
      for (int ks = 0; ks < 2; ++ks) {
        bf16x8 bk = *(const bf16x8*)&sK[sw64(j * 16 + l, ks * 4 + quad)];
        s0 = mfma16(aq[0][ks], bk, s0);
        s1 = mfma16(aq[1][ks], bk, s1);
      }
#pragma unroll
      for (int t = 0; t < 4; ++t)
        accj[j] += exp2c(s0[t] * C2) + exp2c(s1[t] * C2);
    }
  }
#pragma unroll
  for (int j = 0; j < 8; ++j) {
    float v = accj[j];
    v += __shfl_xor(v, 16);
    v += __shfl_xor(v, 32);
    if (lane < 16) atomicAdd(&sL[j * 16 + l], v);
  }
  __syncthreads();
  if (tid < 128) sL[tid] = 1.0f / fmaxf(sL[tid], 1e-20f);
  __syncthreads();

  // write V transposed, scaled, k-permuted:
  // storage pos (chunk base | i) holds logical k = base | kk*16 | quad*4 | t
  // where kk=(i>>2), quad=(k0>>3)&3, t=i&3.
#pragma unroll
  for (int t = 0; t < 4; ++t) {
    int u = t * 256 + tid;
    int d = u >> 4, k0 = (u & 15) * 8;
    bf16x8 pk;
#pragma unroll
    for (int i = 0; i < 8; ++i) {
      int kl = (k0 & ~31) | ((i >> 2) << 4) | (((k0 >> 3) & 3) << 2) | (i & 3);
      float v = (float)sV[sw64(kl, d >> 3) + (d & 7)];
      pk[i] = (bf16_t)(v * sL[kl]);
    }
    *(bf16x8*)&Vts[((size_t)bh * 64 + d) * 1024 + kt * 128 + k0] = pk;
  }
}

// ------------- K3: O[q][d] = sum_k exp2(S[q,k]*C2) * Vts[d][k] ---------------
// S computed TRANSPOSED: st = K-frag x Q-frag -> S^T[k=quad*4+t][q=l].
// P^T fragment directly IS the 16x16x16 PV B-operand (B[n=l][k=quad*4+j]):
// PV runs as 2x K=16 MFMA per 32-k chunk, P never leaves registers.
// Vts A-frag: ONE bf16x8 per (jd,ch); lo/hi halves are the kk=0/1 K=16
// A-fragments (free register aliasing) thanks to the permuted Vts layout.
// BOTH K and Vts tiles staged in LDS via global_load_lds, double-buffered,
// prefetched one full kt ahead -> compute reads only LDS + registers.
// Vts LDS tile [64 d][128 k]: 16B chunk s at row d holds logical chunk
// s^(d&7) (XOR-swizzle via pre-swizzled global source) -> 2-way-free reads.
// 512 threads, LDS 64KB -> 2 blocks/CU -> 16 waves/CU.
__global__ __launch_bounds__(512, 4)
void attn_out_k(const bf16_t* __restrict__ qkv, const bf16_t* __restrict__ Vts,
                bf16_t* __restrict__ attn) {
  __shared__ bf16_t sK[2][128 * 64];  // 16 KB x2: [k][dh], sw64-swizzled
  __shared__ bf16_t sV[2][64 * 128];  // 16 KB x2: [d][k], chunk^= d&7
  const int bh = blockIdx.x, qt = blockIdx.y;  // qt in [0,4): 256 q-rows/block
  const int b = bh >> 4, h = bh & 15;
  const int tid = threadIdx.x, wave = tid >> 6, lane = tid & 63;
  const int l = lane & 15, quad = lane >> 4;
  const bf16_t* qbase = qkv + (size_t)b * 3145728 + h * 64;  // row stride 3072
  const bf16_t* vbase = Vts + (size_t)bh * 65536;            // row stride 1024

  // Q B-fragments (loop-invariant): B[n=q][dk = ks*32 + quad*8 + j]
  bf16x8 bq[2][2];
#pragma unroll
  for (int i = 0; i < 2; ++i)
#pragma unroll
    for (int ks = 0; ks < 2; ++ks)
      bq[i][ks] = *(const bf16x8*)&qbase[(size_t)(qt * 256 + wave * 32 + i * 16 + l) *
                                             3072 + ks * 32 + quad * 8];
  f32x4 o[2][4];  // o[i=qtile][jd=dtile] : D[m=d][n=q]
#pragma unroll
  for (int i = 0; i < 2; ++i)
#pragma unroll
    for (int jd = 0; jd < 4; ++jd) o[i][jd] = f32x4{0.f, 0.f, 0.f, 0.f};

  // stage kt=0 -> buf 0 (K: 1024 chunks; V: 1024 chunks; 2 each per thread)
#pragma unroll
  for (int t = 0; t < 2; ++t) {
    int n = t * 512 + tid;
    int r = n >> 3;
    int kc = ((n & 7) ^ (r + (r >> 3))) & 7;
    gld_lds16(qkv + ((size_t)b * 1024 + r) * 3072 + 1024 + h * 64 + kc * 8,
              sK[0] + n * 8);
    int d = n >> 4, s = n & 15;
    int c = s ^ (d & 7);
    gld_lds16(vbase + (size_t)d * 1024 + c * 8, sV[0] + n * 8);
  }

  for (int kt = 0; kt < 8; ++kt) {
    const int buf = kt & 1;
    __syncthreads();  // drains stage(kt); orders buf^1 refill vs prev reads
    if (kt < 7) {
#pragma unroll
      for (int t = 0; t < 2; ++t) {
        int n = t * 512 + tid;
        int r = n >> 3;
        int kc = ((n & 7) ^ (r + (r >> 3))) & 7;
        gld_lds16(qkv + ((size_t)b * 1024 + (kt + 1) * 128 + r) * 3072 + 1024 +
                      h * 64 + kc * 8,
                  sK[buf ^ 1] + n * 8);
        int d = n >> 4, s = n & 15;
        int c = s ^ (d & 7);
        gld_lds16(vbase + (size_t)d * 1024 + (kt + 1) * 128 + c * 8,
                  sV[buf ^ 1] + n * 8);
      }
    }
    const bf16_t* sKb = sK[buf];
    const bf16_t* sVb = sV[buf];

#pragma unroll
    for (int ch = 0; ch < 4; ++ch) {  // 32-k chunks
      // K A-frags: A[m=k=ch*32+kk*16+l][dk] -- i-invariant, hoisted
      bf16x8 ak[2][2];
#pragma unroll
      for (int kk = 0; kk < 2; ++kk)
#pragma unroll
        for (int ks = 0; ks < 2; ++ks)
          ak[kk][ks] = *(const bf16x8*)&sKb[sw64(ch * 32 + kk * 16 + l,
                                                 ks * 4 + quad)];
      // Vts A-frags from LDS: row d=jd*16+l, logical chunk ch*4+quad,
      // storage chunk = logical ^ (l&7)  (d&7 == l&7 since jd*16%8==0)
      bf16x8 va[4];
#pragma unroll
      for (int jd = 0; jd < 4; ++jd)
        va[jd] = *(const bf16x8*)&sVb[(jd * 16 + l) * 128 +
                                      (((ch * 4 + quad) ^ (l & 7)) << 3)];
#pragma unroll
      for (int i = 0; i < 2; ++i) {  // q-tiles
        // S^T tiles (kk=0,1)
        f32x4 st0 = {0.f, 0.f, 0.f, 0.f}, st1 = {0.f, 0.f, 0.f, 0.f};
        st0 = mfma16(ak[0][0], bq[i][0], st0);
        st0 = mfma16(ak[0][1], bq[i][1], st0);
        st1 = mfma16(ak[1][0], bq[i][0], st1);
        st1 = mfma16(ak[1][1], bq[i][1], st1);
        // P^T = exp2(S^T*C2): k=kk*16+quad*4+t, q=l -- already PV B-layout
        bf16x4 p0, p1;
#pragma unroll
        for (int t = 0; t < 4; ++t) {
          p0[t] = (bf16_t)exp2c(st0[t] * C2);
          p1[t] = (bf16_t)exp2c(st1[t] * C2);
        }
#pragma unroll
        for (int jd = 0; jd < 4; ++jd) {
          o[i][jd] = mfma16k16(lo4(va[jd]), p0, o[i][jd]);
          o[i][jd] = mfma16k16(hi4(va[jd]), p1, o[i][jd]);
        }
      }
    }
  }
  // epilogue: q = qt*256+wave*32+i*16+l, d = jd*16+quad*4+{0..3} -> 8B stores
#pragma unroll
  for (int i = 0; i < 2; ++i) {
    size_t row = (size_t)b * 1024 + qt * 256 + wave * 32 + i * 16 + l;
#pragma unroll
    for (int jd = 0; jd < 4; ++jd) {
      bf16x4 pk;
#pragma unroll
      for (int t = 0; t < 4; ++t) pk[t] = (bf16_t)sanit(o[i][jd][t]);
      *(bf16x4*)&attn[row * 3072 + h * 64 + jd * 16 + quad * 4] = pk;
    }
  }
}

extern "C" void kernel_launch(void* const* d_in, const int* in_sizes, int n_in,
                              void* d_out, int out_size, void* d_ws, size_t ws_size,
                              hipStream_t stream) {
  (void)in_sizes; (void)n_in; (void)out_size; (void)ws_size;
  char* w = (char*)d_ws;
  bf16_t* qkv = (bf16_t*)w;                 // [0, 50331648)
  bf16_t* xb = (bf16_t*)(w + 50331648);     // [50331648, 67108864) -> Vts after K1
  bf16_t* Vts = xb;
  bf16_t* Wqkvb = (bf16_t*)(w + 67108864);  // [67108864, 73400320)
  bf16_t* Wprojb = (bf16_t*)(w + 73400320); // [73400320, 75497472)
  int* flag = (int*)(w + 75497472);
  bf16_t* attn = qkv + 2048;                // V-columns of qkv, stride 3072

  detect_dtype<<<1, 256, 0, stream>>>((const unsigned short*)d_in[0], flag);
  convert_in<<<6144, 256, 0, stream>>>(d_in[0], d_in[1], d_in[2],
                                       xb, Wqkvb, Wprojb, flag);

  // K1: qkv = x @ Wqkv^T  (8192 x 3072, K=1024), grid 1536 (%8==0):
  // many blocks/CU -> single-buffer variant (inter-block overlap).
  gemm_bt<<<dim3(24, 64), 256, 0, stream>>>(xb, 1024, Wqkvb, qkv, nullptr, 3072,
                                            1024, nullptr);
  // K2: column-softmax denominators folded into Vts (permuted layout)
  attn_stats<<<dim3(128, 8), 256, 0, stream>>>(qkv, Vts);
  // K3: attention output -> qkv V-columns (512 thr, 256 q-rows/block)
  attn_out_k<<<dim3(128, 4), 512, 0, stream>>>(qkv, Vts, attn);
  // K4: out = attn @ Wproj^T  (8192 x 1024, K=1024), grid 512 (%8==0):
  // ~2 blocks/CU -> static-dbuf variant (wave-internal overlap).
  gemm_bt_db<<<dim3(8, 64), 256, 0, stream>>>(attn, 3072, Wprojb, (bf16_t*)d_out,
                                              (float*)d_out, 1024, 1024, flag);
}

// Round 9
// 277.651 us; speedup vs baseline: 1.0435x; 1.0435x over previous
//
#include <hip/hip_runtime.h>

// B=8, T=1024, D=1024, H=16, DH=64.
// Column softmax (axis=-2): attn[q,k] = exp(S[q,k])/sum_q' exp(S[q',k]).
// rcpL folded into V (Vts = V * rcpL), so K3 is O = exp2(S*C2) @ Vts.
// K3 computes S TRANSPOSED (A=K, B=Q) so the P fragment exits MFMA with
// q=lane&15 and k=quad*4+t -- which is EXACTLY the B-operand layout of the
// K=16 MFMA (16x16x16_bf16). PV therefore consumes P fully in-register.
// Vts is stored k-PERMUTED (within each 32-chunk: pos quad*8+kk*4+t holds
// logical k=kk*16+quad*4+t) so the PV A-fragment is ONE contiguous bf16x8
// load whose lo/hi halves are the two K=16 A-fragments (free reg aliasing).
// R3: Vts tile staged in LDS (dbuf, global_load_lds, XOR-swizzled).
// R4: runtime-indexed LDS dbuf -> alias-conservative vmcnt drain. REVERTED.
// R6: single-buffer BK=64: K1=64.4us (but R8 re-ran the same body at 77.7us
// -- co-compilation + session noise ~ +-10-20% on absolutes; traffic
// counters are the only noise-free cross-round signal).
// R7: static dbuf both GEMMs: best e2e 270.7us; K1 FETCH doubled to 116MB
// (2 blocks/CU -> ~64 concurrent blocks/XCD span 24 B-panels = 6MB > 4MB L2).
// R9: R7 module + SUPERTILED XCD swizzle: within each XCD chunk, blocks
// ordered in 8row x 8col supertiles -> concurrent working set = 8 A-panels
// + 8 B-panels = 4MB = per-XCD L2. Pure bijective remap, no structure change.

typedef __bf16 bf16_t;
typedef __bf16 bf16x8 __attribute__((ext_vector_type(8)));
typedef __bf16 bf16x4 __attribute__((ext_vector_type(4)));
typedef float f32x4 __attribute__((ext_vector_type(4)));
typedef unsigned short u16x8 __attribute__((ext_vector_type(8)));
typedef short s16x4 __attribute__((ext_vector_type(4)));

#define DEV __device__ __forceinline__
#define C2 0.18033688f  // DH^-0.5 * log2(e)

DEV void gld_lds16(const bf16_t* g, bf16_t* l) {
  __builtin_amdgcn_global_load_lds(
      (const __attribute__((address_space(1))) unsigned int*)g,
      (__attribute__((address_space(3))) unsigned int*)l, 16, 0, 0);
}

// exp2 via v_exp_f32; upper clamp only (underflow->0 fine); finite always.
DEV float exp2c(float x) { return __builtin_amdgcn_exp2f(fminf(x, 30.f)); }
DEV float sanit(float v) { return (v == v) ? fminf(fmaxf(v, -1e4f), 1e4f) : 0.f; }

// Swizzled chunk (8 bf16 = 16B) offsets in elements. Swizzle baked into the
// staging GLOBAL address so the LDS side stays linear (global_load_lds req).
DEV int sw64(int r, int kc) { return r * 64 + (((kc ^ (r + (r >> 3))) & 7) << 3); }

DEV f32x4 mfma16(bf16x8 a, bf16x8 b, f32x4 c) {
  return __builtin_amdgcn_mfma_f32_16x16x32_bf16(a, b, c, 0, 0, 0);
}

// K=16 bf16 MFMA: A[m=l][k=quad*4+j], B[n=l][k=quad*4+j], D row=quad*4+t col=l.
DEV f32x4 mfma16k16(bf16x4 a, bf16x4 b, f32x4 c) {
#if defined(__has_builtin) && __has_builtin(__builtin_amdgcn_mfma_f32_16x16x16bf16_1k)
  union U { bf16x4 h; s16x4 s; };
  U ua, ub;
  ua.h = a;
  ub.h = b;
  return __builtin_amdgcn_mfma_f32_16x16x16bf16_1k(ua.s, ub.s, c, 0, 0, 0);
#else
  f32x4 d;
  asm("v_mfma_f32_16x16x16_bf16 %0, %1, %2, %3"
      : "=v"(d)
      : "v"(a), "v"(b), "v"(c));
  return d;
#endif
}

DEV bf16x4 lo4(bf16x8 v) { return __builtin_shufflevector(v, v, 0, 1, 2, 3); }
DEV bf16x4 hi4(bf16x8 v) { return __builtin_shufflevector(v, v, 4, 5, 6, 7); }

// ---- dtype probe: bf16 data has exp<=~134; fp32 misread shows exp>=160 -----
__global__ void detect_dtype(const unsigned short* x, int* flag) {
  __shared__ int smax;
  if (threadIdx.x == 0) smax = 0;
  __syncthreads();
  int m = 0;
  for (int i = threadIdx.x; i < 16384; i += 256) {
    int e = (x[i] >> 7) & 0xFF;
    m = m > e ? m : e;
  }
  atomicMax(&smax, m);
  __syncthreads();
  if (threadIdx.x == 0) *flag = (smax >= 160) ? 1 : 0;
}

// ---- canonicalize all 3 inputs to bf16 in one kernel ------------------------
__global__ void convert_in(const void* __restrict__ x, const void* __restrict__ wq,
                           const void* __restrict__ wp, bf16_t* __restrict__ xb,
                           bf16_t* __restrict__ wqb, bf16_t* __restrict__ wpb,
                           const int* __restrict__ flag) {
  int i = blockIdx.x * 256 + threadIdx.x;  // vec8 index, total 1572864
  const void* src;
  bf16_t* dst;
  int off;
  if (i < 1048576) { src = x; dst = xb; off = i; }
  else if (i < 1441792) { src = wq; dst = wqb; off = i - 1048576; }
  else { src = wp; dst = wpb; off = i - 1441792; }
  if (*flag) {
    const float4* s = (const float4*)src;
    float4 a = s[off * 2], b = s[off * 2 + 1];
    bf16x8 o;
    o[0] = (bf16_t)a.x; o[1] = (bf16_t)a.y; o[2] = (bf16_t)a.z; o[3] = (bf16_t)a.w;
    o[4] = (bf16_t)b.x; o[5] = (bf16_t)b.y; o[6] = (bf16_t)b.z; o[7] = (bf16_t)b.w;
    *(bf16x8*)(dst + (size_t)off * 8) = o;
  } else {
    ((u16x8*)dst)[off] = ((const u16x8*)src)[off];
  }
}

// --------- C[m][n] = sum_k A[m][k]*B[n][k], 128x128 tile, BK=64x2 -----------
// Statically-unrolled LDS double-buffer (R7 body, best-measured e2e).
// SUPERTILED XCD swizzle: xcd = bid&7 owns a contiguous 8-row band of
// tiles (gridDim.y/8 == 8 rows for both grids); within the band, blocks
// are ordered col-group-major in 8x8 supertiles so the ~64 concurrent
// blocks/XCD touch only 8 A-panels + 8 B-panels = 4MB = per-XCD L2.
// Requires gridDim.y == 64 and gridDim.x % 8 == 0 (24 and 8 both OK).
__global__ __launch_bounds__(256, 2)
void gemm_bt(const bf16_t* __restrict__ A, int lda, const bf16_t* __restrict__ B,
             bf16_t* __restrict__ Cb, float* __restrict__ Cf, int ldc,
             int K, const int* __restrict__ f32flag) {
  __shared__ bf16_t sA0[128 * 64];  // 16 KB
  __shared__ bf16_t sB0[128 * 64];
  __shared__ bf16_t sA1[128 * 64];
  __shared__ bf16_t sB1[128 * 64];
  const int tid = threadIdx.x;
  const int wave = tid >> 6, lane = tid & 63;
  const int l = lane & 15, quad = lane >> 4;
  // supertiled XCD swizzle (bijective):
  //   xcd = bid & 7, rank = bid >> 3 in [0, gy/8 * gx)
  //   colgrp = rank >> 6 (8x8 supertiles), rem = rank & 63
  //   row = xcd*8 + (rem & 7), col = colgrp*8 + (rem >> 3)
  const int bid = blockIdx.y * gridDim.x + blockIdx.x;
  const int rank = bid >> 3, xcd = bid & 7;
  const int rem = rank & 63;
  const int row0 = (xcd * 8 + (rem & 7)) * 128;
  const int col0 = ((rank >> 6) * 8 + (rem >> 3)) * 128;
  const int wm = (wave >> 1) * 64, wn = (wave & 1) * 64;
  f32x4 acc[4][4];
#pragma unroll
  for (int i = 0; i < 4; ++i)
#pragma unroll
    for (int j = 0; j < 4; ++j) acc[i][j] = f32x4{0.f, 0.f, 0.f, 0.f};

#define STAGE_G(sa, sb_, kk)                                                  \
  {                                                                           \
    _Pragma("unroll") for (int t = 0; t < 4; ++t) {                           \
      int n = t * 256 + tid;                                                  \
      int r = n >> 3;                                                         \
      int kc = ((n & 7) ^ (r + (r >> 3))) & 7;                                \
      gld_lds16(A + (size_t)(row0 + r) * lda + (kk) + kc * 8, (sa) + n * 8);  \
      gld_lds16(B + (size_t)(col0 + r) * K + (kk) + kc * 8, (sb_) + n * 8);   \
    }                                                                         \
  }

#define COMPUTE_G(sa, sb_)                                                    \
  {                                                                           \
    _Pragma("unroll") for (int ks = 0; ks < 2; ++ks) {                        \
      bf16x8 af[4], bfr[4];                                                   \
      _Pragma("unroll") for (int i = 0; i < 4; ++i) af[i] =                   \
          *(const bf16x8*)&(sa)[sw64(wm + i * 16 + l, ks * 4 + quad)];        \
      _Pragma("unroll") for (int j = 0; j < 4; ++j) bfr[j] =                  \
          *(const bf16x8*)&(sb_)[sw64(wn + j * 16 + l, ks * 4 + quad)];       \
      _Pragma("unroll") for (int i = 0; i < 4; ++i)                           \
          _Pragma("unroll") for (int j = 0; j < 4; ++j) acc[i][j] =           \
              mfma16(af[i], bfr[j], acc[i][j]);                               \
    }                                                                         \
  }

  STAGE_G(sA0, sB0, 0);
  for (int k0 = 0; k0 < K; k0 += 128) {
    __syncthreads();  // buf0 staged; also orders prev compute(buf1) vs refill
    if (k0 + 64 < K) STAGE_G(sA1, sB1, k0 + 64);
    COMPUTE_G(sA0, sB0);
    __syncthreads();  // buf1 staged; orders compute(buf0) vs buf0 refill
    if (k0 + 128 < K) STAGE_G(sA0, sB0, k0 + 128);
    COMPUTE_G(sA1, sB1);
  }
#undef STAGE_G
#undef COMPUTE_G

  const bool of32 = (f32flag != nullptr) && (*f32flag != 0);
#pragma unroll
  for (int i = 0; i < 4; ++i) {
    int rr = row0 + wm + i * 16 + quad * 4;
#pragma unroll
    for (int j = 0; j < 4; ++j) {
      int cc = col0 + wn + j * 16 + l;
#pragma unroll
      for (int t = 0; t < 4; ++t) {
        float v = sanit(acc[i][j][t]);
        size_t idx = (size_t)(rr + t) * ldc + cc;
        if (of32) Cf[idx] = v; else Cb[idx] = (bf16_t)v;
      }
    }
  }
}

// ------------- K2: column sumexp L[k]; write Vts = V * (1/L) -----------------
// Grid (bh, kt): same-bh blocks spaced 128 apart -> same XCD -> Q of that bh
// stays L2-hot. Per-lane accj[] defers reduction: 8 atomics/wave.
// Vts write is k-PERMUTED within each 32-chunk (see K3 header comment).
__global__ __launch_bounds__(256, 4)
void attn_stats(const bf16_t* __restrict__ qkv, bf16_t* __restrict__ Vts) {
  __shared__ bf16_t sK[128 * 64];
  __shared__ bf16_t sV[128 * 64];
  __shared__ float sL[128];
  const int bh = blockIdx.x, kt = blockIdx.y;
  const int b = bh >> 4, h = bh & 15;
  const int tid = threadIdx.x, wave = tid >> 6, lane = tid & 63;
  const int l = lane & 15, quad = lane >> 4;
  const size_t rowK = (size_t)b * 1024 + kt * 128;

  // stage V-tile and K-tile (swizzled)
#pragma unroll
  for (int t = 0; t < 4; ++t) {
    int base = wave * 256 + t * 64;
    int n = base + lane;
    int r = n >> 3;
    int kc = ((n & 7) ^ (r + (r >> 3))) & 7;
    gld_lds16(qkv + (rowK + r) * 3072 + 2048 + h * 64 + kc * 8, sV + base * 8);
    gld_lds16(qkv + (rowK + r) * 3072 + 1024 + h * 64 + kc * 8, sK + base * 8);
  }
  if (tid < 128) sL[tid] = 0.f;
  __syncthreads();

  float accj[8];
#pragma unroll
  for (int j = 0; j < 8; ++j) accj[j] = 0.f;

  for (int qt = 0; qt < 8; ++qt) {
    bf16x8 aq[2][2];
#pragma unroll
    for (int i = 0; i < 2; ++i)
#pragma unroll
      for (int ks = 0; ks < 2; ++ks)
        aq[i][ks] = *(const bf16x8*)&qkv[((size_t)b * 1024 + qt * 128 + wave * 32 +
                                          i * 16 + l) * 3072 + h * 64 +
                                         (ks * 4 + quad) * 8];
#pragma unroll
    for (int j = 0; j < 8; ++j) {
      f32x4 s0 = {0.f, 0.f, 0.f, 0.f}, s1 = {0.f, 0.f, 0.f, 0.f};
#pragma unroll
      for (int ks = 0; ks < 2; ++ks) {
        bf16x8 bk = *(const bf16x8*)&sK[sw64(j * 16 + l, ks * 4 + quad)];
        s0 = mfma16(aq[0][ks], bk, s0);
        s1 = mfma16(aq[1][ks], bk, s1);
      }
#pragma unroll
      for (int t = 0; t < 4; ++t)
        accj[j] += exp2c(s0[t] * C2) + exp2c(s1[t] * C2);
    }
  }
#pragma unroll
  for (int j = 0; j < 8; ++j) {
    float v = accj[j];
    v += __shfl_xor(v, 16);
    v += __shfl_xor(v, 32);
    if (lane < 16) atomicAdd(&sL[j * 16 + l], v);
  }
  __syncthreads();
  if (tid < 128) sL[tid] = 1.0f / fmaxf(sL[tid], 1e-20f);
  __syncthreads();

  // write V transposed, scaled, k-permuted:
  // storage pos (chunk base | i) holds logical k = base | kk*16 | quad*4 | t
  // where kk=(i>>2), quad=(k0>>3)&3, t=i&3.
#pragma unroll
  for (int t = 0; t < 4; ++t) {
    int u = t * 256 + tid;
    int d = u >> 4, k0 = (u & 15) * 8;
    bf16x8 pk;
#pragma unroll
    for (int i = 0; i < 8; ++i) {
      int kl = (k0 & ~31) | ((i >> 2) << 4) | (((k0 >> 3) & 3) << 2) | (i & 3);
      float v = (float)sV[sw64(kl, d >> 3) + (d & 7)];
      pk[i] = (bf16_t)(v * sL[kl]);
    }
    *(bf16x8*)&Vts[((size_t)bh * 64 + d) * 1024 + kt * 128 + k0] = pk;
  }
}

// ------------- K3: O[q][d] = sum_k exp2(S[q,k]*C2) * Vts[d][k] ---------------
// S computed TRANSPOSED: st = K-frag x Q-frag -> S^T[k=quad*4+t][q=l].
// P^T fragment directly IS the 16x16x16 PV B-operand (B[n=l][k=quad*4+j]):
// PV runs as 2x K=16 MFMA per 32-k chunk, P never leaves registers.
// Vts A-frag: ONE bf16x8 per (jd,ch); lo/hi halves are the kk=0/1 K=16
// A-fragments (free register aliasing) thanks to the permuted Vts layout.
// BOTH K and Vts tiles staged in LDS via global_load_lds, double-buffered,
// prefetched one full kt ahead -> compute reads only LDS + registers.
// Vts LDS tile [64 d][128 k]: 16B chunk s at row d holds logical chunk
// s^(d&7) (XOR-swizzle via pre-swizzled global source) -> 2-way-free reads.
// 512 threads, LDS 64KB -> 2 blocks/CU -> 16 waves/CU.
__global__ __launch_bounds__(512, 4)
void attn_out_k(const bf16_t* __restrict__ qkv, const bf16_t* __restrict__ Vts,
                bf16_t* __restrict__ attn) {
  __shared__ bf16_t sK[2][128 * 64];  // 16 KB x2: [k][dh], sw64-swizzled
  __shared__ bf16_t sV[2][64 * 128];  // 16 KB x2: [d][k], chunk^= d&7
  const int bh = blockIdx.x, qt = blockIdx.y;  // qt in [0,4): 256 q-rows/block
  const int b = bh >> 4, h = bh & 15;
  const int tid = threadIdx.x, wave = tid >> 6, lane = tid & 63;
  const int l = lane & 15, quad = lane >> 4;
  const bf16_t* qbase = qkv + (size_t)b * 3145728 + h * 64;  // row stride 3072
  const bf16_t* vbase = Vts + (size_t)bh * 65536;            // row stride 1024

  // Q B-fragments (loop-invariant): B[n=q][dk = ks*32 + quad*8 + j]
  bf16x8 bq[2][2];
#pragma unroll
  for (int i = 0; i < 2; ++i)
#pragma unroll
    for (int ks = 0; ks < 2; ++ks)
      bq[i][ks] = *(const bf16x8*)&qbase[(size_t)(qt * 256 + wave * 32 + i * 16 + l) *
                                             3072 + ks * 32 + quad * 8];
  f32x4 o[2][4];  // o[i=qtile][jd=dtile] : D[m=d][n=q]
#pragma unroll
  for (int i = 0; i < 2; ++i)
#pragma unroll
    for (int jd = 0; jd < 4; ++jd) o[i][jd] = f32x4{0.f, 0.f, 0.f, 0.f};

  // stage kt=0 -> buf 0 (K: 1024 chunks; V: 1024 chunks; 2 each per thread)
#pragma unroll
  for (int t = 0; t < 2; ++t) {
    int n = t * 512 + tid;
    int r = n >> 3;
    int kc = ((n & 7) ^ (r + (r >> 3))) & 7;
    gld_lds16(qkv + ((size_t)b * 1024 + r) * 3072 + 1024 + h * 64 + kc * 8,
              sK[0] + n * 8);
    int d = n >> 4, s = n & 15;
    int c = s ^ (d & 7);
    gld_lds16(vbase + (size_t)d * 1024 + c * 8, sV[0] + n * 8);
  }

  for (int kt = 0; kt < 8; ++kt) {
    const int buf = kt & 1;
    __syncthreads();  // drains stage(kt); orders buf^1 refill vs prev reads
    if (kt < 7) {
#pragma unroll
      for (int t = 0; t < 2; ++t) {
        int n = t * 512 + tid;
        int r = n >> 3;
        int kc = ((n & 7) ^ (r + (r >> 3))) & 7;
        gld_lds16(qkv + ((size_t)b * 1024 + (kt + 1) * 128 + r) * 3072 + 1024 +
                      h * 64 + kc * 8,
                  sK[buf ^ 1] + n * 8);
        int d = n >> 4, s = n & 15;
        int c = s ^ (d & 7);
        gld_lds16(vbase + (size_t)d * 1024 + (kt + 1) * 128 + c * 8,
                  sV[buf ^ 1] + n * 8);
      }
    }
    const bf16_t* sKb = sK[buf];
    const bf16_t* sVb = sV[buf];

#pragma unroll
    for (int ch = 0; ch < 4; ++ch) {  // 32-k chunks
      // K A-frags: A[m=k=ch*32+kk*16+l][dk] -- i-invariant, hoisted
      bf16x8 ak[2][2];
#pragma unroll
      for (int kk = 0; kk < 2; ++kk)
#pragma unroll
        for (int ks = 0; ks < 2; ++ks)
          ak[kk][ks] = *(const bf16x8*)&sKb[sw64(ch * 32 + kk * 16 + l,
                                                 ks * 4 + quad)];
      // Vts A-frags from LDS: row d=jd*16+l, logical chunk ch*4+quad,
      // storage chunk = logical ^ (l&7)  (d&7 == l&7 since jd*16%8==0)
      bf16x8 va[4];
#pragma unroll
      for (int jd = 0; jd < 4; ++jd)
        va[jd] = *(const bf16x8*)&sVb[(jd * 16 + l) * 128 +
                                      (((ch * 4 + quad) ^ (l & 7)) << 3)];
#pragma unroll
      for (int i = 0; i < 2; ++i) {  // q-tiles
        // S^T tiles (kk=0,1)
        f32x4 st0 = {0.f, 0.f, 0.f, 0.f}, st1 = {0.f, 0.f, 0.f, 0.f};
        st0 = mfma16(ak[0][0], bq[i][0], st0);
        st0 = mfma16(ak[0][1], bq[i][1], st0);
        st1 = mfma16(ak[1][0], bq[i][0], st1);
        st1 = mfma16(ak[1][1], bq[i][1], st1);
        // P^T = exp2(S^T*C2): k=kk*16+quad*4+t, q=l -- already PV B-layout
        bf16x4 p0, p1;
#pragma unroll
        for (int t = 0; t < 4; ++t) {
          p0[t] = (bf16_t)exp2c(st0[t] * C2);
          p1[t] = (bf16_t)exp2c(st1[t] * C2);
        }
#pragma unroll
        for (int jd = 0; jd < 4; ++jd) {
          o[i][jd] = mfma16k16(lo4(va[jd]), p0, o[i][jd]);
          o[i][jd] = mfma16k16(hi4(va[jd]), p1, o[i][jd]);
        }
      }
    }
  }
  // epilogue: q = qt*256+wave*32+i*16+l, d = jd*16+quad*4+{0..3} -> 8B stores
#pragma unroll
  for (int i = 0; i < 2; ++i) {
    size_t row = (size_t)b * 1024 + qt * 256 + wave * 32 + i * 16 + l;
#pragma unroll
    for (int jd = 0; jd < 4; ++jd) {
      bf16x4 pk;
#pragma unroll
      for (int t = 0; t < 4; ++t) pk[t] = (bf16_t)sanit(o[i][jd][t]);
      *(bf16x4*)&attn[row * 3072 + h * 64 + jd * 16 + quad * 4] = pk;
    }
  }
}

extern "C" void kernel_launch(void* const* d_in, const int* in_sizes, int n_in,
                              void* d_out, int out_size, void* d_ws, size_t ws_size,
                              hipStream_t stream) {
  (void)in_sizes; (void)n_in; (void)out_size; (void)ws_size;
  char* w = (char*)d_ws;
  bf16_t* qkv = (bf16_t*)w;                 // [0, 50331648)
  bf16_t* xb = (bf16_t*)(w + 50331648);     // [50331648, 67108864) -> Vts after K1
  bf16_t* Vts = xb;
  bf16_t* Wqkvb = (bf16_t*)(w + 67108864);  // [67108864, 73400320)
  bf16_t* Wprojb = (bf16_t*)(w + 73400320); // [73400320, 75497472)
  int* flag = (int*)(w + 75497472);
  bf16_t* attn = qkv + 2048;                // V-columns of qkv, stride 3072

  detect_dtype<<<1, 256, 0, stream>>>((const unsigned short*)d_in[0], flag);
  convert_in<<<6144, 256, 0, stream>>>(d_in[0], d_in[1], d_in[2],
                                       xb, Wqkvb, Wprojb, flag);

  // K1: qkv = x @ Wqkv^T  (8192 x 3072, K=1024), grid 24x64 (gy=64, gx%8==0)
  gemm_bt<<<dim3(24, 64), 256, 0, stream>>>(xb, 1024, Wqkvb, qkv, nullptr, 3072,
                                            1024, nullptr);
  // K2: column-softmax denominators folded into Vts (permuted layout)
  attn_stats<<<dim3(128, 8), 256, 0, stream>>>(qkv, Vts);
  // K3: attention output -> qkv V-columns (512 thr, 256 q-rows/block)
  attn_out_k<<<dim3(128, 4), 512, 0, stream>>>(qkv, Vts, attn);
  // K4: out = attn @ Wproj^T  (8192 x 1024, K=1024), grid 8x64
  gemm_bt<<<dim3(8, 64), 256, 0, stream>>>(attn, 3072, Wprojb, (bf16_t*)d_out,
                                           (float*)d_out, 1024, 1024, flag);
}

// Round 10
// 266.425 us; speedup vs baseline: 1.0875x; 1.0421x over previous
//
#include <hip/hip_runtime.h>

// B=8, T=1024, D=1024, H=16, DH=64.
// Column softmax (axis=-2): attn[q,k] = exp(S[q,k])/sum_q' exp(S[q',k]).
// rcpL folded into V (Vts = V * rcpL), so K3 is O = exp2(S*C2) @ Vts.
// K3 computes S TRANSPOSED (A=K, B=Q) so the P fragment exits MFMA with
// q=lane&15 and k=quad*4+t. Vts is stored k-PERMUTED (within each 32-chunk:
// pos quad*8+j holds logical k = j<4 ? quad*4+j : 16+quad*4+(j-4)) -- which
// is EXACTLY the per-lane k-set of a 16x16x32 MFMA operand. So PV runs as
// ONE K=32 MFMA per (jd): A = va[jd] (bf16x8 straight from LDS), B = p0||p1
// (the two QK S^T fragments exp'd and concatenated in-register). P never
// leaves registers; no K=16 MFMAs needed at all (R10).
// R3: K/Vts tiles staged in LDS (dbuf, global_load_lds, XOR-swizzled).
// R4: runtime-indexed LDS dbuf in gemm -> alias-conservative drain. REVERTED.
// R6-R9 consolidated: all 2-phase GEMM scheduling variants land in a
// 64-81us noise band (R6 vs R8: identical binary, 64.4 vs 77.7). K1 is at
// the 2-phase structural ceiling; FETCH-cutting (R9 supertile, 116->48.7MB)
// doesn't help because the kernel is latency- not BW-bound. Config pinned
// to the best-measured module: R7 (static dbuf both GEMMs, chunked swizzle).
// R10: K3 PV 8xK16 -> 4xK32 (strictly fewer instructions, same math) +
// s_setprio(1) around K3's compute cluster (T5).

typedef __bf16 bf16_t;
typedef __bf16 bf16x8 __attribute__((ext_vector_type(8)));
typedef __bf16 bf16x4 __attribute__((ext_vector_type(4)));
typedef float f32x4 __attribute__((ext_vector_type(4)));
typedef unsigned short u16x8 __attribute__((ext_vector_type(8)));

#define DEV __device__ __forceinline__
#define C2 0.18033688f  // DH^-0.5 * log2(e)

DEV void gld_lds16(const bf16_t* g, bf16_t* l) {
  __builtin_amdgcn_global_load_lds(
      (const __attribute__((address_space(1))) unsigned int*)g,
      (__attribute__((address_space(3))) unsigned int*)l, 16, 0, 0);
}

// exp2 via v_exp_f32; upper clamp only (underflow->0 fine); finite always.
DEV float exp2c(float x) { return __builtin_amdgcn_exp2f(fminf(x, 30.f)); }
DEV float sanit(float v) { return (v == v) ? fminf(fmaxf(v, -1e4f), 1e4f) : 0.f; }

// Swizzled chunk (8 bf16 = 16B) offsets in elements. Swizzle baked into the
// staging GLOBAL address so the LDS side stays linear (global_load_lds req).
DEV int sw64(int r, int kc) { return r * 64 + (((kc ^ (r + (r >> 3))) & 7) << 3); }

DEV f32x4 mfma16(bf16x8 a, bf16x8 b, f32x4 c) {
  return __builtin_amdgcn_mfma_f32_16x16x32_bf16(a, b, c, 0, 0, 0);
}

// ---- dtype probe: bf16 data has exp<=~134; fp32 misread shows exp>=160 -----
__global__ void detect_dtype(const unsigned short* x, int* flag) {
  __shared__ int smax;
  if (threadIdx.x == 0) smax = 0;
  __syncthreads();
  int m = 0;
  for (int i = threadIdx.x; i < 16384; i += 256) {
    int e = (x[i] >> 7) & 0xFF;
    m = m > e ? m : e;
  }
  atomicMax(&smax, m);
  __syncthreads();
  if (threadIdx.x == 0) *flag = (smax >= 160) ? 1 : 0;
}

// ---- canonicalize all 3 inputs to bf16 in one kernel ------------------------
__global__ void convert_in(const void* __restrict__ x, const void* __restrict__ wq,
                           const void* __restrict__ wp, bf16_t* __restrict__ xb,
                           bf16_t* __restrict__ wqb, bf16_t* __restrict__ wpb,
                           const int* __restrict__ flag) {
  int i = blockIdx.x * 256 + threadIdx.x;  // vec8 index, total 1572864
  const void* src;
  bf16_t* dst;
  int off;
  if (i < 1048576) { src = x; dst = xb; off = i; }
  else if (i < 1441792) { src = wq; dst = wqb; off = i - 1048576; }
  else { src = wp; dst = wpb; off = i - 1441792; }
  if (*flag) {
    const float4* s = (const float4*)src;
    float4 a = s[off * 2], b = s[off * 2 + 1];
    bf16x8 o;
    o[0] = (bf16_t)a.x; o[1] = (bf16_t)a.y; o[2] = (bf16_t)a.z; o[3] = (bf16_t)a.w;
    o[4] = (bf16_t)b.x; o[5] = (bf16_t)b.y; o[6] = (bf16_t)b.z; o[7] = (bf16_t)b.w;
    *(bf16x8*)(dst + (size_t)off * 8) = o;
  } else {
    ((u16x8*)dst)[off] = ((const u16x8*)src)[off];
  }
}

// --------- C[m][n] = sum_k A[m][k]*B[n][k], 128x128 tile, BK=64x2 -----------
// Statically-unrolled LDS double-buffer (R7 body, best-measured e2e):
//   barrier; stage(buf1,k+64); compute(buf0); barrier; stage(buf0,k+128);
//   compute(buf1).  4 distinct __shared__ arrays -> alias analysis resolves
// (R4 lesson). Chunked bijective XCD swizzle (nwg % 8 == 0).
__global__ __launch_bounds__(256, 2)
void gemm_bt(const bf16_t* __restrict__ A, int lda, const bf16_t* __restrict__ B,
             bf16_t* __restrict__ Cb, float* __restrict__ Cf, int ldc,
             int K, const int* __restrict__ f32flag) {
  __shared__ bf16_t sA0[128 * 64];  // 16 KB
  __shared__ bf16_t sB0[128 * 64];
  __shared__ bf16_t sA1[128 * 64];
  __shared__ bf16_t sB1[128 * 64];
  const int tid = threadIdx.x;
  const int wave = tid >> 6, lane = tid & 63;
  const int l = lane & 15, quad = lane >> 4;
  const int nwg = gridDim.x * gridDim.y;
  const int bid = blockIdx.y * gridDim.x + blockIdx.x;
  const int sb = (bid & 7) * (nwg >> 3) + (bid >> 3);
  const int row0 = (sb / gridDim.x) * 128, col0 = (sb % gridDim.x) * 128;
  const int wm = (wave >> 1) * 64, wn = (wave & 1) * 64;
  f32x4 acc[4][4];
#pragma unroll
  for (int i = 0; i < 4; ++i)
#pragma unroll
    for (int j = 0; j < 4; ++j) acc[i][j] = f32x4{0.f, 0.f, 0.f, 0.f};

#define STAGE_G(sa, sb_, kk)                                                  \
  {                                                                           \
    _Pragma("unroll") for (int t = 0; t < 4; ++t) {                           \
      int n = t * 256 + tid;                                                  \
      int r = n >> 3;                                                         \
      int kc = ((n & 7) ^ (r + (r >> 3))) & 7;                                \
      gld_lds16(A + (size_t)(row0 + r) * lda + (kk) + kc * 8, (sa) + n * 8);  \
      gld_lds16(B + (size_t)(col0 + r) * K + (kk) + kc * 8, (sb_) + n * 8);   \
    }                                                                         \
  }

#define COMPUTE_G(sa, sb_)                                                    \
  {                                                                           \
    _Pragma("unroll") for (int ks = 0; ks < 2; ++ks) {                        \
      bf16x8 af[4], bfr[4];                                                   \
      _Pragma("unroll") for (int i = 0; i < 4; ++i) af[i] =                   \
          *(const bf16x8*)&(sa)[sw64(wm + i * 16 + l, ks * 4 + quad)];        \
      _Pragma("unroll") for (int j = 0; j < 4; ++j) bfr[j] =                  \
          *(const bf16x8*)&(sb_)[sw64(wn + j * 16 + l, ks * 4 + quad)];       \
      _Pragma("unroll") for (int i = 0; i < 4; ++i)                           \
          _Pragma("unroll") for (int j = 0; j < 4; ++j) acc[i][j] =           \
              mfma16(af[i], bfr[j], acc[i][j]);                               \
    }                                                                         \
  }

  STAGE_G(sA0, sB0, 0);
  for (int k0 = 0; k0 < K; k0 += 128) {
    __syncthreads();  // buf0 staged; also orders prev compute(buf1) vs refill
    if (k0 + 64 < K) STAGE_G(sA1, sB1, k0 + 64);
    COMPUTE_G(sA0, sB0);
    __syncthreads();  // buf1 staged; orders compute(buf0) vs buf0 refill
    if (k0 + 128 < K) STAGE_G(sA0, sB0, k0 + 128);
    COMPUTE_G(sA1, sB1);
  }
#undef STAGE_G
#undef COMPUTE_G

  const bool of32 = (f32flag != nullptr) && (*f32flag != 0);
#pragma unroll
  for (int i = 0; i < 4; ++i) {
    int rr = row0 + wm + i * 16 + quad * 4;
#pragma unroll
    for (int j = 0; j < 4; ++j) {
      int cc = col0 + wn + j * 16 + l;
#pragma unroll
      for (int t = 0; t < 4; ++t) {
        float v = sanit(acc[i][j][t]);
        size_t idx = (size_t)(rr + t) * ldc + cc;
        if (of32) Cf[idx] = v; else Cb[idx] = (bf16_t)v;
      }
    }
  }
}

// ------------- K2: column sumexp L[k]; write Vts = V * (1/L) -----------------
// Grid (bh, kt): same-bh blocks spaced 128 apart -> same XCD -> Q of that bh
// stays L2-hot. Per-lane accj[] defers reduction: 8 atomics/wave.
// Vts write is k-PERMUTED within each 32-chunk (see K3 header comment).
__global__ __launch_bounds__(256, 4)
void attn_stats(const bf16_t* __restrict__ qkv, bf16_t* __restrict__ Vts) {
  __shared__ bf16_t sK[128 * 64];
  __shared__ bf16_t sV[128 * 64];
  __shared__ float sL[128];
  const int bh = blockIdx.x, kt = blockIdx.y;
  const int b = bh >> 4, h = bh & 15;
  const int tid = threadIdx.x, wave = tid >> 6, lane = tid & 63;
  const int l = lane & 15, quad = lane >> 4;
  const size_t rowK = (size_t)b * 1024 + kt * 128;

  // stage V-tile and K-tile (swizzled)
#pragma unroll
  for (int t = 0; t < 4; ++t) {
    int base = wave * 256 + t * 64;
    int n = base + lane;
    int r = n >> 3;
    int kc = ((n & 7) ^ (r + (r >> 3))) & 7;
    gld_lds16(qkv + (rowK + r) * 3072 + 2048 + h * 64 + kc * 8, sV + base * 8);
    gld_lds16(qkv + (rowK + r) * 3072 + 1024 + h * 64 + kc * 8, sK + base * 8);
  }
  if (tid < 128) sL[tid] = 0.f;
  __syncthreads();

  float accj[8];
#pragma unroll
  for (int j = 0; j < 8; ++j) accj[j] = 0.f;

  for (int qt = 0; qt < 8; ++qt) {
    bf16x8 aq[2][2];
#pragma unroll
    for (int i = 0; i < 2; ++i)
#pragma unroll
      for (int ks = 0; ks < 2; ++ks)
        aq[i][ks] = *(const bf16x8*)&qkv[((size_t)b * 1024 + qt * 128 + wave * 32 +
                                          i * 16 + l) * 3072 + h * 64 +
                                         (ks * 4 + quad) * 8];
#pragma unroll
    for (int j = 0; j < 8; ++j) {
      f32x4 s0 = {0.f, 0.f, 0.f, 0.f}, s1 = {0.f, 0.f, 0.f, 0.f};
#pragma unroll
      for (int ks = 0; ks < 2; ++ks) {
        bf16x8 bk = *(const bf16x8*)&sK[sw64(j * 16 + l, ks * 4 + quad)];
        s0 = mfma16(aq[0][ks], bk, s0);
        s1 = mfma16(aq[1][ks], bk, s1);
      }
#pragma unroll
      for (int t = 0; t < 4; ++t)
        accj[j] += exp2c(s0[t] * C2) + exp2c(s1[t] * C2);
    }
  }
#pragma unroll
  for (int j = 0; j < 8; ++j) {
    float v = accj[j];
    v += __shfl_xor(v, 16);
    v += __shfl_xor(v, 32);
    if (lane < 16) atomicAdd(&sL[j * 16 + l], v);
  }
  __syncthreads();
  if (tid < 128) sL[tid] = 1.0f / fmaxf(sL[tid], 1e-20f);
  __syncthreads();

  // write V transposed, scaled, k-permuted:
  // storage pos (chunk base | i) holds logical k = base | kk*16 | quad*4 | t
  // where kk=(i>>2), quad=(k0>>3)&3, t=i&3.
#pragma unroll
  for (int t = 0; t < 4; ++t) {
    int u = t * 256 + tid;
    int d = u >> 4, k0 = (u & 15) * 8;
    bf16x8 pk;
#pragma unroll
    for (int i = 0; i < 8; ++i) {
      int kl = (k0 & ~31) | ((i >> 2) << 4) | (((k0 >> 3) & 3) << 2) | (i & 3);
      float v = (float)sV[sw64(kl, d >> 3) + (d & 7)];
      pk[i] = (bf16_t)(v * sL[kl]);
    }
    *(bf16x8*)&Vts[((size_t)bh * 64 + d) * 1024 + kt * 128 + k0] = pk;
  }
}

// ------------- K3: O[q][d] = sum_k exp2(S[q,k]*C2) * Vts[d][k] ---------------
// S computed TRANSPOSED: st = K-frag x Q-frag -> S^T[k=quad*4+t][q=l].
// PV is a single K=32 MFMA per (jd): the concatenated P fragment
// pc = {exp(st0[0..3]), exp(st1[0..3])} occupies B[n=l][slot=quad*8+j],
// and Vts' permuted storage puts the SAME logical k at A[m=d][slot] --
// the slot->k bijection cancels inside the contraction. (R10; replaces
// the 2x K=16 workaround -- half the PV MFMA issues, identical math.)
// BOTH K and Vts tiles staged in LDS via global_load_lds, double-buffered,
// prefetched one full kt ahead -> compute reads only LDS + registers.
// Vts LDS tile [64 d][128 k]: 16B chunk s at row d holds logical chunk
// s^(d&7) (XOR-swizzle via pre-swizzled global source) -> 2-way-free reads.
// 512 threads, LDS 64KB -> 2 blocks/CU -> 16 waves/CU. T5 setprio around
// the per-i MFMA+exp cluster.
__global__ __launch_bounds__(512, 4)
void attn_out_k(const bf16_t* __restrict__ qkv, const bf16_t* __restrict__ Vts,
                bf16_t* __restrict__ attn) {
  __shared__ bf16_t sK[2][128 * 64];  // 16 KB x2: [k][dh], sw64-swizzled
  __shared__ bf16_t sV[2][64 * 128];  // 16 KB x2: [d][k], chunk^= d&7
  const int bh = blockIdx.x, qt = blockIdx.y;  // qt in [0,4): 256 q-rows/block
  const int b = bh >> 4, h = bh & 15;
  const int tid = threadIdx.x, wave = tid >> 6, lane = tid & 63;
  const int l = lane & 15, quad = lane >> 4;
  const bf16_t* qbase = qkv + (size_t)b * 3145728 + h * 64;  // row stride 3072
  const bf16_t* vbase = Vts + (size_t)bh * 65536;            // row stride 1024

  // Q B-fragments (loop-invariant): B[n=q][dk = ks*32 + quad*8 + j]
  bf16x8 bq[2][2];
#pragma unroll
  for (int i = 0; i < 2; ++i)
#pragma unroll
    for (int ks = 0; ks < 2; ++ks)
      bq[i][ks] = *(const bf16x8*)&qbase[(size_t)(qt * 256 + wave * 32 + i * 16 + l) *
                                             3072 + ks * 32 + quad * 8];
  f32x4 o[2][4];  // o[i=qtile][jd=dtile] : D[m=d][n=q]
#pragma unroll
  for (int i = 0; i < 2; ++i)
#pragma unroll
    for (int jd = 0; jd < 4; ++jd) o[i][jd] = f32x4{0.f, 0.f, 0.f, 0.f};

  // stage kt=0 -> buf 0 (K: 1024 chunks; V: 1024 chunks; 2 each per thread)
#pragma unroll
  for (int t = 0; t < 2; ++t) {
    int n = t * 512 + tid;
    int r = n >> 3;
    int kc = ((n & 7) ^ (r + (r >> 3))) & 7;
    gld_lds16(qkv + ((size_t)b * 1024 + r) * 3072 + 1024 + h * 64 + kc * 8,
              sK[0] + n * 8);
    int d = n >> 4, s = n & 15;
    int c = s ^ (d & 7);
    gld_lds16(vbase + (size_t)d * 1024 + c * 8, sV[0] + n * 8);
  }

  for (int kt = 0; kt < 8; ++kt) {
    const int buf = kt & 1;
    __syncthreads();  // drains stage(kt); orders buf^1 refill vs prev reads
    if (kt < 7) {
#pragma unroll
      for (int t = 0; t < 2; ++t) {
        int n = t * 512 + tid;
        int r = n >> 3;
        int kc = ((n & 7) ^ (r + (r >> 3))) & 7;
        gld_lds16(qkv + ((size_t)b * 1024 + (kt + 1) * 128 + r) * 3072 + 1024 +
                      h * 64 + kc * 8,
                  sK[buf ^ 1] + n * 8);
        int d = n >> 4, s = n & 15;
        int c = s ^ (d & 7);
        gld_lds16(vbase + (size_t)d * 1024 + (kt + 1) * 128 + c * 8,
                  sV[buf ^ 1] + n * 8);
      }
    }
    const bf16_t* sKb = sK[buf];
    const bf16_t* sVb = sV[buf];

#pragma unroll
    for (int ch = 0; ch < 4; ++ch) {  // 32-k chunks
      // K A-frags: A[m=k=ch*32+kk*16+l][dk] -- i-invariant, hoisted
      bf16x8 ak[2][2];
#pragma unroll
      for (int kk = 0; kk < 2; ++kk)
#pragma unroll
        for (int ks = 0; ks < 2; ++ks)
          ak[kk][ks] = *(const bf16x8*)&sKb[sw64(ch * 32 + kk * 16 + l,
                                                 ks * 4 + quad)];
      // Vts A-frags from LDS: row d=jd*16+l, logical chunk ch*4+quad,
      // storage chunk = logical ^ (l&7)  (d&7 == l&7 since jd*16%8==0)
      bf16x8 va[4];
#pragma unroll
      for (int jd = 0; jd < 4; ++jd)
        va[jd] = *(const bf16x8*)&sVb[(jd * 16 + l) * 128 +
                                      (((ch * 4 + quad) ^ (l & 7)) << 3)];
#pragma unroll
      for (int i = 0; i < 2; ++i) {  // q-tiles
        __builtin_amdgcn_s_setprio(1);
        // S^T tiles (kk=0,1)
        f32x4 st0 = {0.f, 0.f, 0.f, 0.f}, st1 = {0.f, 0.f, 0.f, 0.f};
        st0 = mfma16(ak[0][0], bq[i][0], st0);
        st0 = mfma16(ak[0][1], bq[i][1], st0);
        st1 = mfma16(ak[1][0], bq[i][0], st1);
        st1 = mfma16(ak[1][1], bq[i][1], st1);
        // pc = exp2(S^T*C2) concatenated: slot quad*8+j <-> Vts storage slot
        bf16x8 pc;
#pragma unroll
        for (int t = 0; t < 4; ++t) {
          pc[t] = (bf16_t)exp2c(st0[t] * C2);
          pc[4 + t] = (bf16_t)exp2c(st1[t] * C2);
        }
#pragma unroll
        for (int jd = 0; jd < 4; ++jd)
          o[i][jd] = mfma16(va[jd], pc, o[i][jd]);
        __builtin_amdgcn_s_setprio(0);
      }
    }
  }
  // epilogue: q = qt*256+wave*32+i*16+l, d = jd*16+quad*4+{0..3} -> 8B stores
#pragma unroll
  for (int i = 0; i < 2; ++i) {
    size_t row = (size_t)b * 1024 + qt * 256 + wave * 32 + i * 16 + l;
#pragma unroll
    for (int jd = 0; jd < 4; ++jd) {
      bf16x4 pk;
#pragma unroll
      for (int t = 0; t < 4; ++t) pk[t] = (bf16_t)sanit(o[i][jd][t]);
      *(bf16x4*)&attn[row * 3072 + h * 64 + jd * 16 + quad * 4] = pk;
    }
  }
}

extern "C" void kernel_launch(void* const* d_in, const int* in_sizes, int n_in,
                              void* d_out, int out_size, void* d_ws, size_t ws_size,
                              hipStream_t stream) {
  (void)in_sizes; (void)n_in; (void)out_size; (void)ws_size;
  char* w = (char*)d_ws;
  bf16_t* qkv = (bf16_t*)w;                 // [0, 50331648)
  bf16_t* xb = (bf16_t*)(w + 50331648);     // [50331648, 67108864) -> Vts after K1
  bf16_t* Vts = xb;
  bf16_t* Wqkvb = (bf16_t*)(w + 67108864);  // [67108864, 73400320)
  bf16_t* Wprojb = (bf16_t*)(w + 73400320); // [73400320, 75497472)
  int* flag = (int*)(w + 75497472);
  bf16_t* attn = qkv + 2048;                // V-columns of qkv, stride 3072

  detect_dtype<<<1, 256, 0, stream>>>((const unsigned short*)d_in[0], flag);
  convert_in<<<6144, 256, 0, stream>>>(d_in[0], d_in[1], d_in[2],
                                       xb, Wqkvb, Wprojb, flag);

  // K1: qkv = x @ Wqkv^T  (8192 x 3072, K=1024), grid 24*64=1536 (%8==0)
  gemm_bt<<<dim3(24, 64), 256, 0, stream>>>(xb, 1024, Wqkvb, qkv, nullptr, 3072,
                                            1024, nullptr);
  // K2: column-softmax denominators folded into Vts (permuted layout)
  attn_stats<<<dim3(128, 8), 256, 0, stream>>>(qkv, Vts);
  // K3: attention output -> qkv V-columns (512 thr, 256 q-rows/block)
  attn_out_k<<<dim3(128, 4), 512, 0, stream>>>(qkv, Vts, attn);
  // K4: out = attn @ Wproj^T  (8192 x 1024, K=1024), grid 8*64=512 (%8==0)
  gemm_bt<<<dim3(8, 64), 256, 0, stream>>>(attn, 3072, Wprojb, (bf16_t*)d_out,
                                           (float*)d_out, 1024, 1024, flag);
}